// Round 1
// baseline (3886.324 us; speedup 1.0000x reference)
//
#include <hip/hip_runtime.h>
#include <cmath>

#define HIDDEN 256
#define NRAD   16
#define OUTDIM 128
#define NNODES 50000

// ---------------------------------------------------------------------------
// Kernel A: fused gate + scatter-add.
//   g[e][c] = (sum_r rbf[e][r] * W_rbf[r][c]) * x[e][c];  h[i[e]][c] += g
// Block = 256 threads = 4 waves. Each wave processes one edge per iteration;
// lane l covers columns 4l..4l+3 (float4 loads on x, float4 reads on LDS W).
// ---------------------------------------------------------------------------
__global__ __launch_bounds__(256) void gate_scatter_kernel(
    const float* __restrict__ x, const float* __restrict__ rbf,
    const int* __restrict__ idx, const float* __restrict__ W_rbf,
    float* __restrict__ h, int E, int edges_per_block)
{
    __shared__ float wr[NRAD * HIDDEN];  // 16 KB
    const int tid = threadIdx.x;
    // Stage W_rbf into LDS (coalesced: each thread 16 elements, stride 256)
    #pragma unroll
    for (int r = 0; r < NRAD; ++r)
        wr[r * HIDDEN + tid] = W_rbf[r * HIDDEN + tid];
    __syncthreads();

    const int wave = tid >> 6;        // 0..3
    const int lane = tid & 63;        // 0..63
    const int c0   = lane * 4;        // column base (4 cols per lane)

    const int e0 = blockIdx.x * edges_per_block;
    const int e1 = min(e0 + edges_per_block, E);

    for (int e = e0 + wave; e < e1; e += 4) {
        const int node = idx[e];
        // rbf row: wave-uniform -> scalar loads
        float rb[NRAD];
        #pragma unroll
        for (int r = 0; r < NRAD; ++r) rb[r] = rbf[(long)e * NRAD + r];

        float4 acc = make_float4(0.f, 0.f, 0.f, 0.f);
        #pragma unroll
        for (int r = 0; r < NRAD; ++r) {
            const float4 w = *(const float4*)&wr[r * HIDDEN + c0];
            acc.x = fmaf(rb[r], w.x, acc.x);
            acc.y = fmaf(rb[r], w.y, acc.y);
            acc.z = fmaf(rb[r], w.z, acc.z);
            acc.w = fmaf(rb[r], w.w, acc.w);
        }
        const float4 xv = *(const float4*)&x[(long)e * HIDDEN + c0];
        float* hp = &h[(long)node * HIDDEN + c0];
        atomicAdd(hp + 0, acc.x * xv.x);
        atomicAdd(hp + 1, acc.y * xv.y);
        atomicAdd(hp + 2, acc.z * xv.z);
        atomicAdd(hp + 3, acc.w * xv.w);
    }
}

// ---------------------------------------------------------------------------
// Kernel B: fp32 GEMM C[M,N] = A[M,256] @ W[256,N] (+bias, +swish)
// BM=128, BN=64, BK=16; 256 threads (16x16), thread tile 8x4.
// ---------------------------------------------------------------------------
template<int N, bool BIAS_SWISH>
__global__ __launch_bounds__(256) void gemm_fused_kernel(
    const float* __restrict__ A, const float* __restrict__ W,
    const float* __restrict__ bias, float* __restrict__ C, int M)
{
    constexpr int BM = 128, BN = 64, BK = 16, K = HIDDEN;
    __shared__ float As[BK][BM + 4];  // +4 pad keeps 16B alignment, breaks stride
    __shared__ float Bs[BK][BN];

    const int tid = threadIdx.x;
    const int m0 = blockIdx.x * BM;
    const int n0 = blockIdx.y * BN;
    const int tx = tid & 15;          // 0..15 -> 4 cols each
    const int ty = tid >> 4;          // 0..15 -> 8 rows each

    // A-tile load coords: 128 rows x 16 cols, float4 along k, two passes
    const int arow = tid >> 2;        // 0..63
    const int acol = (tid & 3) << 2;  // 0,4,8,12
    // B-tile load coords: 16 rows x 64 cols, float4 along n
    const int brow = tid >> 4;        // 0..15
    const int bcol = (tid & 15) << 2; // 0..60

    float acc[8][4] = {};

    for (int k0 = 0; k0 < K; k0 += BK) {
        #pragma unroll
        for (int p = 0; p < 2; ++p) {
            const int row = m0 + arow + p * 64;
            float4 v = make_float4(0.f, 0.f, 0.f, 0.f);
            if (row < M)
                v = *(const float4*)&A[(long)row * K + k0 + acol];
            As[acol + 0][arow + p * 64] = v.x;
            As[acol + 1][arow + p * 64] = v.y;
            As[acol + 2][arow + p * 64] = v.z;
            As[acol + 3][arow + p * 64] = v.w;
        }
        {
            const float4 v = *(const float4*)&W[(long)(k0 + brow) * N + n0 + bcol];
            *(float4*)&Bs[brow][bcol] = v;
        }
        __syncthreads();

        #pragma unroll
        for (int kk = 0; kk < BK; ++kk) {
            float a[8], b[4];
            #pragma unroll
            for (int i = 0; i < 8; ++i) a[i] = As[kk][ty * 8 + i];
            #pragma unroll
            for (int j = 0; j < 4; ++j) b[j] = Bs[kk][tx * 4 + j];
            #pragma unroll
            for (int i = 0; i < 8; ++i)
                #pragma unroll
                for (int j = 0; j < 4; ++j)
                    acc[i][j] = fmaf(a[i], b[j], acc[i][j]);
        }
        __syncthreads();
    }

    // Epilogue: bias + swish, float4 stores
    #pragma unroll
    for (int i = 0; i < 8; ++i) {
        const int row = m0 + ty * 8 + i;
        if (row >= M) continue;
        float4 v = make_float4(acc[i][0], acc[i][1], acc[i][2], acc[i][3]);
        if (BIAS_SWISH) {
            const int col = n0 + tx * 4;
            v.x += bias[col + 0];
            v.y += bias[col + 1];
            v.z += bias[col + 2];
            v.w += bias[col + 3];
            v.x = v.x / (1.f + expf(-v.x));
            v.y = v.y / (1.f + expf(-v.y));
            v.z = v.z / (1.f + expf(-v.z));
            v.w = v.w / (1.f + expf(-v.w));
        }
        *(float4*)&C[(long)row * N + n0 + tx * 4] = v;
    }
}

// ---------------------------------------------------------------------------
extern "C" void kernel_launch(void* const* d_in, const int* in_sizes, int n_in,
                              void* d_out, int out_size, void* d_ws, size_t ws_size,
                              hipStream_t stream) {
    const float* x     = (const float*)d_in[0];   // [E,256]
    const float* rbf   = (const float*)d_in[1];   // [E,16]
    const int*   idx   = (const int*)d_in[2];     // [E]
    // d_in[3] = num_nodes scalar (fixed = 50000, hardcoded)
    const float* W_rbf = (const float*)d_in[4];   // [16,256]
    const float* Ws    = (const float*)d_in[5];   // [3,256,256]
    const float* bs    = (const float*)d_in[6];   // [3,256]
    const float* W_out = (const float*)d_in[7];   // [256,128]
    float* out = (float*)d_out;                    // [50000,128]

    const int E = in_sizes[0] / HIDDEN;           // 800000
    const int M = NNODES;                          // 50000

    const size_t hbytes = (size_t)M * HIDDEN * sizeof(float);  // 51.2 MB
    float* h0 = (float*)d_ws;
    float* h1 = (float*)((char*)d_ws + hbytes);

    // Zero scatter target (ws is re-poisoned to 0xAA before every call)
    hipMemsetAsync(h0, 0, hbytes, stream);

    // Fused gate + scatter
    const int EPB = 16;
    const int gblocks = (E + EPB - 1) / EPB;
    gate_scatter_kernel<<<gblocks, 256, 0, stream>>>(x, rbf, idx, W_rbf, h0, E, EPB);

    // MLP: 3 x (GEMM 256x256 + bias + swish), ping-pong h0<->h1
    const dim3 gemm_grid((M + 127) / 128, HIDDEN / 64);
    gemm_fused_kernel<HIDDEN, true><<<gemm_grid, 256, 0, stream>>>(
        h0, Ws + 0 * HIDDEN * HIDDEN, bs + 0 * HIDDEN, h1, M);
    gemm_fused_kernel<HIDDEN, true><<<gemm_grid, 256, 0, stream>>>(
        h1, Ws + 1 * HIDDEN * HIDDEN, bs + 1 * HIDDEN, h0, M);
    gemm_fused_kernel<HIDDEN, true><<<gemm_grid, 256, 0, stream>>>(
        h0, Ws + 2 * HIDDEN * HIDDEN, bs + 2 * HIDDEN, h1, M);

    // Final projection -> d_out [50000,128], no bias/activation
    const dim3 out_grid((M + 127) / 128, OUTDIM / 64);
    gemm_fused_kernel<OUTDIM, false><<<out_grid, 256, 0, stream>>>(
        h1, W_out, nullptr, out, M);
}